// Round 13
// baseline (423.927 us; speedup 1.0000x reference)
//
#include <hip/hip_runtime.h>
#include <stdint.h>

typedef unsigned long long u64;
typedef unsigned int u32;
typedef unsigned short u16;

#define D_      256
#define K_      1024
#define N_      131072
#define RB      64
#define MARGIN  0.024f

using short8 = __attribute__((ext_vector_type(8))) short;
using f32x4  = __attribute__((ext_vector_type(4))) float;

__device__ __forceinline__ u16 f2bf(float f) {
    u32 x = __float_as_uint(f);
    return (u16)((x + 0x7fffu + ((x >> 16) & 1u)) >> 16);
}
__device__ __forceinline__ float sqr_rn(float x) { return __fmul_rn(x, x); }
__device__ __forceinline__ float med3(float a, float b, float c) {
    return __builtin_amdgcn_fmed3f(a, b, c);
}

// numpy pairwise sum of squares over 256 elements (bitwise identical to rounds 1/3/5/6/8)
__device__ __forceinline__ float np_pairwise_sq_256(const float* p) {
    float tot[2];
#pragma unroll
    for (int blk = 0; blk < 2; ++blk) {
        const float* q = p + blk * 128;
        float r[8];
#pragma unroll
        for (int j = 0; j < 8; ++j) r[j] = sqr_rn(q[j]);
        for (int i = 8; i < 128; i += 8) {
#pragma unroll
            for (int j = 0; j < 8; ++j) r[j] = __fadd_rn(r[j], sqr_rn(q[i + j]));
        }
        tot[blk] = __fadd_rn(__fadd_rn(__fadd_rn(r[0], r[1]), __fadd_rn(r[2], r[3])),
                             __fadd_rn(__fadd_rn(r[4], r[5]), __fadd_rn(r[6], r[7])));
    }
    return __fadd_rn(tot[0], tot[1]);
}

// ------- prep (merged): E image (-2E bf16, d-major) + esq (np-pairwise) + flag_cnt=0 -------
__global__ __launch_bounds__(256)
void prep_all(const float* __restrict__ E, u16* __restrict__ EhImg,
              float* __restrict__ esq, u32* __restrict__ flag_cnt) {
    int idx  = blockIdx.x * 256 + threadIdx.x;   // 8192 tasks
    if (idx == 0) flag_cnt[0] = 0u;
    int code = idx >> 3, dc = idx & 7;
    int ct = code >> 8, lc = code & 255;
    const float4* e4 = (const float4*)(E + (size_t)code * D_ + dc * 32);
    char* tile = (char*)EhImg + ((size_t)(ct * 8 + dc) << 14);
#pragma unroll
    for (int dch = 0; dch < 4; ++dch) {
        float4 v0 = e4[dch * 2], v1 = e4[dch * 2 + 1];
        u32 a = (u32)f2bf(-2.0f * v0.x) | ((u32)f2bf(-2.0f * v0.y) << 16);
        u32 b = (u32)f2bf(-2.0f * v0.z) | ((u32)f2bf(-2.0f * v0.w) << 16);
        u32 c = (u32)f2bf(-2.0f * v1.x) | ((u32)f2bf(-2.0f * v1.y) << 16);
        u32 d = (u32)f2bf(-2.0f * v1.z) | ((u32)f2bf(-2.0f * v1.w) << 16);
        *(uint4*)(tile + (dch * 256 + lc) * 16) = make_uint4(a, b, c, d);
    }
    if (dc == 0) esq[code] = np_pairwise_sq_256(E + (size_t)code * D_);
}

// ------- prep: exact f32 transposed codebook ET[d][k] -------
__global__ __launch_bounds__(256)
void prep_et(const float* __restrict__ E, float* __restrict__ ET) {
    int t = blockIdx.x * 256 + threadIdx.x;   // 262144
    int d = t >> 10, k = t & 1023;
    ET[t] = E[(size_t)k * D_ + d];
}

// ---------------- main: top-3, zero-barrier k-loop, depth-1 B loads (low VGPR) ------------
// 64 rows x 1024 codes, 8 waves (2r x 4c). B-frags read directly from L2-resident EhImg
// at the top of each (fully unrolled) dc step — compiler pipelines within the reg budget.
// No bv double-buffer => worst-case pressure fits the (512,4) 64-reg cap (r10 spill fix).
__global__ __launch_bounds__(512, 4)
void vq_main(const float* __restrict__ Z, const u16* __restrict__ EhImg,
             const float* __restrict__ esq_g, const float* __restrict__ E,
             u32* __restrict__ flag_cnt, u32* __restrict__ flag_list,
             u32* __restrict__ cand_g, float* __restrict__ out) {
    extern __shared__ char smem[];
    char*  zhb   = smem;                      // 32768: [64 rows][512B], byte-xor swizzle
    float* wtrip = (float*)(smem + 32768);    // [4 wc][64 row][3] = 3072
    u32*   kst   = (u32*)(smem + 35840);      // 256    (total 36096 B)

    const int t    = threadIdx.x;
    const int lane = t & 63;
    const int wv   = t >> 6;
    const int wr   = wv >> 2;
    const int wc   = wv & 3;
    const int col  = lane & 15;
    const int g    = lane >> 4;
    const int r0   = blockIdx.x * RB;
    const int asw  = (lane & 7) << 4;

    const float4* Z4 = (const float4*)(Z + (size_t)r0 * D_);
#pragma unroll
    for (int q = 0; q < 8; ++q) {
        int idx = t + 512 * q;
        int row = idx >> 6, c4 = idx & 63;
        float4 v = Z4[(size_t)row * 64 + c4];
        u32 lo = (u32)f2bf(v.x) | ((u32)f2bf(v.y) << 16);
        u32 hi = (u32)f2bf(v.z) | ((u32)f2bf(v.w) << 16);
        int boff = (c4 * 8) ^ ((row & 7) << 4);
        *(uint2*)(zhb + row * 512 + boff) = make_uint2(lo, hi);
    }
    __syncthreads();

    const char* ebase = (const char*)EhImg;
    const int   loff  = g * 4096 + wc * 1024 + col * 16;
    const u32   cbase = (u32)(wc * 64 + col);

    float trip[2][4][3];
#pragma unroll
    for (int rf = 0; rf < 2; ++rf)
#pragma unroll
        for (int i = 0; i < 4; ++i) {
            trip[rf][i][0] = 3.0e38f; trip[rf][i][1] = 3.0e38f; trip[rf][i][2] = 3.0e38f;
        }

    f32x4 acc[2][4];

    for (int ct = 0; ct < 4; ++ct) {
#pragma unroll
        for (int cf = 0; cf < 4; ++cf) {
            float ev = esq_g[ct * 256 + wc * 64 + cf * 16 + col];
#pragma unroll
            for (int rf = 0; rf < 2; ++rf)
                acc[rf][cf] = (f32x4){ev, ev, ev, ev};
        }
#pragma unroll
        for (int dc = 0; dc < 8; ++dc) {
            // depth-1 B load from L2-resident image (compiler pipelines across unroll)
            const char* tb = ebase + ((size_t)(ct * 8 + dc) << 14) + loff;
            short8 b[4];
#pragma unroll
            for (int cf = 0; cf < 4; ++cf)
                b[cf] = *(const short8*)(tb + cf * 256);

            const int kb = dc * 64 + g * 16;
            short8 a[2];
#pragma unroll
            for (int rf = 0; rf < 2; ++rf) {
                int row = wr * 32 + rf * 16 + col;
                a[rf] = *(const short8*)(zhb + row * 512 + (kb ^ asw));
            }
#pragma unroll
            for (int rf = 0; rf < 2; ++rf)
#pragma unroll
                for (int cf = 0; cf < 4; ++cf)
                    acc[rf][cf] = __builtin_amdgcn_mfma_f32_16x16x32_bf16(
                        a[rf], b[cf], acc[rf][cf], 0, 0, 0);

            if (dc == 7) {
                const u32 cc0 = ((u32)ct << 8) + cbase;
                // insert 32 scores into per-row sorted top-3 (idx in low 10 mantissa bits)
#pragma unroll
                for (int rf = 0; rf < 2; ++rf)
#pragma unroll
                    for (int cf = 0; cf < 4; ++cf)
#pragma unroll
                        for (int i = 0; i < 4; ++i) {
                            u32 sb = (__float_as_uint(acc[rf][cf][i]) & 0xFFFFFC00u)
                                     | (cc0 + (u32)(cf * 16));
                            float key = __uint_as_float(sb);
                            float b0 = trip[rf][i][0], b1 = trip[rf][i][1],
                                  b2 = trip[rf][i][2];
                            trip[rf][i][0] = fminf(b0, key);
                            trip[rf][i][1] = med3(b0, b1, key);
                            trip[rf][i][2] = med3(b1, b2, key);
                        }
            }
        }
    }

    // ---- in-wave merge of sorted triples across the 16 cols (r8-proven) ----
#pragma unroll
    for (int st = 1; st <= 8; st <<= 1) {
#pragma unroll
        for (int rf = 0; rf < 2; ++rf)
#pragma unroll
            for (int i = 0; i < 4; ++i) {
                float a0 = trip[rf][i][0], a1 = trip[rf][i][1], a2 = trip[rf][i][2];
                float b0 = __shfl_xor(a0, st, 64);
                float b1 = __shfl_xor(a1, st, 64);
                float b2 = __shfl_xor(a2, st, 64);
                float m0 = fminf(a0, b0);
                float x  = fmaxf(a0, b0);
                float y  = fminf(a1, b1);
                float m1 = fminf(x, y);
                float z  = fmaxf(x, y);
                float w  = fminf(a2, b2);
                trip[rf][i][0] = m0;
                trip[rf][i][1] = m1;
                trip[rf][i][2] = fminf(z, w);
            }
    }
    if (col == 0) {
#pragma unroll
        for (int rf = 0; rf < 2; ++rf)
#pragma unroll
            for (int i = 0; i < 4; ++i) {
                int row = wr * 32 + rf * 16 + g * 4 + i;
                float* wp = wtrip + (wc * 64 + row) * 3;
                wp[0] = trip[rf][i][0];
                wp[1] = trip[rf][i][1];
                wp[2] = trip[rf][i][2];
            }
    }
    __syncthreads();

    // ---- finalize (r8-exact): per row merge 4 wave-triples; winner / flag decision ----
    // (>8 survivors within margin ⇒ some wave has 3 within margin ⇒ m0 fires ⇒ safe)
    if (t < RB) {
        float v[4][3];
#pragma unroll
        for (int w = 0; w < 4; ++w) {
            const float* wp = wtrip + (w * 64 + t) * 3;
            v[w][0] = wp[0]; v[w][1] = wp[1]; v[w][2] = wp[2];
        }
        float s1 = fminf(fminf(v[0][0], v[1][0]), fminf(v[2][0], v[3][0]));
        float thr = __fadd_rn(s1, MARGIN);
        bool m0 = (v[0][2] <= thr) | (v[1][2] <= thr) | (v[2][2] <= thr) | (v[3][2] <= thr);
        u32 surv[8];
        int sc = 0;
#pragma unroll
        for (int w = 0; w < 4; ++w)
#pragma unroll
            for (int j = 0; j < 3; ++j) {
                if (v[w][j] <= thr && sc < 8) {
                    surv[sc] = __float_as_uint(v[w][j]) & 1023u;
                    ++sc;
                }
            }
        u32 row_g = (u32)(r0 + t);
        u32 win = __float_as_uint(s1) & 1023u;
        if (m0) {
            u32 pos = atomicAdd(flag_cnt, 1u);
            flag_list[pos] = row_g;                          // mode 0 = full scan
        } else if (sc >= 2) {
            u32 pos = atomicAdd(flag_cnt, 1u);
            flag_list[pos] = row_g | ((u32)sc << 20);
            for (int j = 0; j < sc; ++j) cand_g[(size_t)row_g * 8 + j] = surv[j];
        }
        kst[t] = win;
    }
    __syncthreads();

    const float4* E4 = (const float4*)E;
    float4* O4 = (float4*)out;
#pragma unroll
    for (int q = 0; q < 8; ++q) {
        int idx = t + 512 * q;
        int row = idx >> 6, f4 = idx & 63;
        u32 k = kst[row] & 1023u;
        O4[(size_t)(r0 + row) * 64 + f4] = E4[(size_t)k * 64 + f4];
    }
}

// ---------------- resolve: ET coalesced full scan + 8-lane candidate dots (r12) ----------
__device__ __forceinline__ u64 exact_key_serial(const float4* __restrict__ zr4,
                                                const float* __restrict__ E,
                                                const float* __restrict__ esq,
                                                float zs, u32 k) {
    const float4* er4 = (const float4*)(E + (size_t)k * D_);
    float c = 0.f;
#pragma unroll 8
    for (int q = 0; q < 64; ++q) {
        float4 a = zr4[q], b = er4[q];
        c = fmaf(a.x, b.x, c);
        c = fmaf(a.y, b.y, c);
        c = fmaf(a.z, b.z, c);
        c = fmaf(a.w, b.w, c);
    }
    float dist = __fadd_rn(__fsub_rn(zs, __fmul_rn(2.0f, c)), esq[k]);
    return ((u64)__float_as_uint(dist) << 32) | (u64)k;
}

__global__ __launch_bounds__(256)
void resolve_kernel(const float* __restrict__ Z, const float* __restrict__ E,
                    const float* __restrict__ esq, const u32* __restrict__ flag_cnt,
                    const u32* __restrict__ flag_list,
                    const u32* __restrict__ cand_g, const float* __restrict__ ET,
                    int use_et, float* __restrict__ out) {
    __shared__ float zbuf[4][256];
    const int lane = threadIdx.x & 63;
    const int wsl  = threadIdx.x >> 6;
    const int wid  = (blockIdx.x * 256 + threadIdx.x) >> 6;
    const int nw   = (gridDim.x * 256) >> 6;
    const u32 nf = flag_cnt[0];

    const int grp = lane >> 3, sub = lane & 7;
    const float4* E4 = (const float4*)E;
    float4* O4 = (float4*)out;

    for (u32 i = wid; i < nf; i += nw) {
        u32 e    = flag_list[i];
        u32 row  = e & 0xFFFFFu;
        u32 mode = e >> 20;
        const float* zr = Z + (size_t)row * D_;
        const float4* zr4 = (const float4*)zr;

        float r = 0.f;
        {
            int cidx = lane & 15, blk = cidx >> 3, j = cidx & 7;
            if (lane < 16) {
                const float* q = zr + blk * 128 + j;
                r = sqr_rn(q[0]);
                for (int ii = 8; ii < 128; ii += 8) r = __fadd_rn(r, sqr_rn(q[ii]));
            }
        }
        {
            float o = __shfl_xor(r, 1, 64);  r = __fadd_rn(r, o);
            o = __shfl_xor(r, 2, 64);        r = __fadd_rn(r, o);
            o = __shfl_xor(r, 4, 64);        r = __fadd_rn(r, o);
            o = __shfl_xor(r, 8, 64);        r = __fadd_rn(r, o);
        }
        float zs = __shfl(r, 0, 64);

        u64 best = ~0ull;
        if (mode == 0u) {
            if (use_et) {
                *(float4*)&zbuf[wsl][lane * 4] = zr4[lane];
                asm volatile("s_waitcnt lgkmcnt(0)" ::: "memory");
                const float4* ET4 = (const float4*)ET;
#pragma unroll
                for (int b = 0; b < 4; ++b) {
                    int k0 = b * 256 + lane * 4;
                    float c0 = 0.f, c1 = 0.f, c2 = 0.f, c3 = 0.f;
#pragma unroll 4
                    for (int d = 0; d < 256; ++d) {
                        float zd = zbuf[wsl][d];
                        float4 ev = ET4[d * 256 + b * 64 + lane];
                        c0 = fmaf(zd, ev.x, c0);
                        c1 = fmaf(zd, ev.y, c1);
                        c2 = fmaf(zd, ev.z, c2);
                        c3 = fmaf(zd, ev.w, c3);
                    }
                    float cc[4] = {c0, c1, c2, c3};
#pragma unroll
                    for (int j = 0; j < 4; ++j) {
                        u32 k = (u32)(k0 + j);
                        float dist = __fadd_rn(__fsub_rn(zs, __fmul_rn(2.0f, cc[j])), esq[k]);
                        u64 key = ((u64)__float_as_uint(dist) << 32) | (u64)k;
                        if (key < best) best = key;
                    }
                }
            } else {
                for (u32 k = (u32)lane; k < (u32)K_; k += 64u) {
                    u64 key = exact_key_serial(zr4, E, esq, zs, k);
                    if (key < best) best = key;
                }
            }
#pragma unroll
            for (int off = 32; off >= 1; off >>= 1) {
                u64 o = __shfl_xor(best, off, 64);
                if (o < best) best = o;
            }
        } else {
            if ((u32)grp < mode) {
                u32 k = cand_g[(size_t)row * 8 + grp];
                const float4* er4 = (const float4*)(E + (size_t)k * D_);
                float c = 0.f;
#pragma unroll
                for (int q = 0; q < 8; ++q) {
                    float4 a = zr4[sub * 8 + q], b = er4[sub * 8 + q];
                    c = fmaf(a.x, b.x, c);
                    c = fmaf(a.y, b.y, c);
                    c = fmaf(a.z, b.z, c);
                    c = fmaf(a.w, b.w, c);
                }
                c = __fadd_rn(c, __shfl_xor(c, 1, 64));
                c = __fadd_rn(c, __shfl_xor(c, 2, 64));
                c = __fadd_rn(c, __shfl_xor(c, 4, 64));
                float dist = __fadd_rn(__fsub_rn(zs, __fmul_rn(2.0f, c)), esq[k]);
                best = ((u64)__float_as_uint(dist) << 32) | (u64)k;
            }
            {
                u64 o = __shfl_xor(best, 8, 64);  if (o < best) best = o;
                o = __shfl_xor(best, 16, 64);     if (o < best) best = o;
                o = __shfl_xor(best, 32, 64);     if (o < best) best = o;
            }
        }
        u32 kw = (u32)(best & 0xffffffffu);
        O4[(size_t)row * 64 + lane] = E4[(size_t)kw * 64 + lane];
    }
}

extern "C" void kernel_launch(void* const* d_in, const int* in_sizes, int n_in,
                              void* d_out, int out_size, void* d_ws, size_t ws_size,
                              hipStream_t stream) {
    const float* Z = (const float*)d_in[0];
    const float* E = (const float*)d_in[1];
    float* out = (float*)d_out;

    float* esq       = (float*)d_ws;                              // 4 KB
    u16*   EhImg     = (u16*)((char*)d_ws + 4096);                // 512 KB
    u32*   flag_cnt  = (u32*)((char*)d_ws + 528384);              // 256 B
    u32*   flag_list = (u32*)((char*)d_ws + 528640);              // 512 KB
    u32*   cand_g    = (u32*)((char*)d_ws + 1052928);             // 4 MB
    float* ET        = (float*)((char*)d_ws + 5247232);           // 1 MB (if it fits)
    int use_et = (ws_size >= (size_t)(5247232 + 1048576)) ? 1 : 0;

    prep_all<<<(K_ * 8) / 256, 256, 0, stream>>>(E, EhImg, esq, flag_cnt);
    if (use_et)
        prep_et<<<(K_ * D_) / 256, 256, 0, stream>>>(E, ET);

    const int SMEM = 36096;
    hipFuncSetAttribute((const void*)vq_main,
                        hipFuncAttributeMaxDynamicSharedMemorySize, SMEM);
    vq_main<<<N_ / RB, 512, SMEM, stream>>>(Z, EhImg, esq, E,
                                            flag_cnt, flag_list, cand_g, out);

    resolve_kernel<<<1024, 256, 0, stream>>>(Z, E, esq, flag_cnt, flag_list,
                                             cand_g, ET, use_et, out);
}

// Round 14
// 377.447 us; speedup vs baseline: 1.1231x; 1.1231x over previous
//
#include <hip/hip_runtime.h>
#include <stdint.h>

typedef unsigned long long u64;
typedef unsigned int u32;
typedef unsigned short u16;

#define D_      256
#define K_      1024
#define N_      131072
#define RB      64
#define MARGIN  0.024f
#define CAP     16

using short8 = __attribute__((ext_vector_type(8))) short;
using f32x4  = __attribute__((ext_vector_type(4))) float;

__device__ __forceinline__ u16 f2bf(float f) {
    u32 x = __float_as_uint(f);
    return (u16)((x + 0x7fffu + ((x >> 16) & 1u)) >> 16);
}
__device__ __forceinline__ float sqr_rn(float x) { return __fmul_rn(x, x); }

// numpy pairwise sum of squares over 256 elements (bitwise identical to rounds 1/3/5/6/8)
__device__ __forceinline__ float np_pairwise_sq_256(const float* p) {
    float tot[2];
#pragma unroll
    for (int blk = 0; blk < 2; ++blk) {
        const float* q = p + blk * 128;
        float r[8];
#pragma unroll
        for (int j = 0; j < 8; ++j) r[j] = sqr_rn(q[j]);
        for (int i = 8; i < 128; i += 8) {
#pragma unroll
            for (int j = 0; j < 8; ++j) r[j] = __fadd_rn(r[j], sqr_rn(q[i + j]));
        }
        tot[blk] = __fadd_rn(__fadd_rn(__fadd_rn(r[0], r[1]), __fadd_rn(r[2], r[3])),
                             __fadd_rn(__fadd_rn(r[4], r[5]), __fadd_rn(r[6], r[7])));
    }
    return __fadd_rn(tot[0], tot[1]);
}

// ------- prep (merged): E image (-2E bf16, d-major) + esq (np-pairwise) + flag_cnt=0 -------
__global__ __launch_bounds__(256)
void prep_all(const float* __restrict__ E, u16* __restrict__ EhImg,
              float* __restrict__ esq, u32* __restrict__ flag_cnt) {
    int idx  = blockIdx.x * 256 + threadIdx.x;   // 8192 tasks
    if (idx == 0) flag_cnt[0] = 0u;
    int code = idx >> 3, dc = idx & 7;
    int ct = code >> 8, lc = code & 255;
    const float4* e4 = (const float4*)(E + (size_t)code * D_ + dc * 32);
    char* tile = (char*)EhImg + ((size_t)(ct * 8 + dc) << 14);
#pragma unroll
    for (int dch = 0; dch < 4; ++dch) {
        float4 v0 = e4[dch * 2], v1 = e4[dch * 2 + 1];
        u32 a = (u32)f2bf(-2.0f * v0.x) | ((u32)f2bf(-2.0f * v0.y) << 16);
        u32 b = (u32)f2bf(-2.0f * v0.z) | ((u32)f2bf(-2.0f * v0.w) << 16);
        u32 c = (u32)f2bf(-2.0f * v1.x) | ((u32)f2bf(-2.0f * v1.y) << 16);
        u32 d = (u32)f2bf(-2.0f * v1.z) | ((u32)f2bf(-2.0f * v1.w) << 16);
        *(uint4*)(tile + (dch * 256 + lc) * 16) = make_uint4(a, b, c, d);
    }
    if (dc == 0) esq[code] = np_pairwise_sq_256(E + (size_t)code * D_);
}

// ------- prep: exact f32 transposed codebook ET[d][k] -------
__global__ __launch_bounds__(256)
void prep_et(const float* __restrict__ E, float* __restrict__ ET) {
    int t = blockIdx.x * 256 + threadIdx.x;   // 262144
    int d = t >> 10, k = t & 1023;
    ET[t] = E[(size_t)k * D_ + d];
}

// ---------------- main: zero-barrier k-loop + wave-local-threshold LDS append -------------
// 64 rows x 1024 codes, 8 waves (2r x 4c). B-frags from L2-resident EhImg (depth-1).
// Per wave: running per-row min over its own codes (8 VGPR, intra-group shfl only).
// Appends (score,idx) via LDS atomics — NO barriers in the k-loop. Final prune at end.
__global__ __launch_bounds__(512, 4)
void vq_main(const float* __restrict__ Z, const u16* __restrict__ EhImg,
             const float* __restrict__ esq_g, const float* __restrict__ E,
             u32* __restrict__ flag_cnt, u32* __restrict__ flag_list,
             u32* __restrict__ cand_g, float* __restrict__ out) {
    extern __shared__ char smem[];
    char*  zhb    = smem;                       // 32768: [64 rows][512B], byte-xor swizzle
    float* cand_s = (float*)(smem + 32768);     // 64*16*4 = 4096
    u32*   cand_i = (u32*)(smem + 36864);       // 4096
    u32*   cnt    = (u32*)(smem + 40960);       // 256
    u32*   kst    = (u32*)(smem + 41216);       // 256   (total 41472 B)

    const int t    = threadIdx.x;
    const int lane = t & 63;
    const int wv   = t >> 6;
    const int wr   = wv >> 2;        // 0..1: 32-row band
    const int wc   = wv & 3;         // 0..3: 64-code band
    const int col  = lane & 15;
    const int g    = lane >> 4;      // row subgroup
    const int r0   = blockIdx.x * RB;
    const int asw  = (lane & 7) << 4;

    if (t < RB) cnt[t] = 0u;

    // ---- stage z tile (f32 -> bf16, row-major 512B rows, xor swizzle) ----
    const float4* Z4 = (const float4*)(Z + (size_t)r0 * D_);
#pragma unroll
    for (int q = 0; q < 8; ++q) {
        int idx = t + 512 * q;
        int row = idx >> 6, c4 = idx & 63;
        float4 v = Z4[(size_t)row * 64 + c4];
        u32 lo = (u32)f2bf(v.x) | ((u32)f2bf(v.y) << 16);
        u32 hi = (u32)f2bf(v.z) | ((u32)f2bf(v.w) << 16);
        int boff = (c4 * 8) ^ ((row & 7) << 4);
        *(uint2*)(zhb + row * 512 + boff) = make_uint2(lo, hi);
    }
    __syncthreads();   // z + cnt visible; no more barriers until after the k-loop

    const char* ebase = (const char*)EhImg;
    const int   loff  = g * 4096 + wc * 1024 + col * 16;
    const u32   cbase = (u32)(wc * 64 + col);

    float wrun[2][4];   // running per-row min over THIS wave's codes (upper bound of global)
#pragma unroll
    for (int rf = 0; rf < 2; ++rf)
#pragma unroll
        for (int i = 0; i < 4; ++i) wrun[rf][i] = 3.0e38f;

    f32x4 acc[2][4];

    for (int ct = 0; ct < 4; ++ct) {
#pragma unroll
        for (int cf = 0; cf < 4; ++cf) {
            float ev = esq_g[ct * 256 + wc * 64 + cf * 16 + col];
#pragma unroll
            for (int rf = 0; rf < 2; ++rf)
                acc[rf][cf] = (f32x4){ev, ev, ev, ev};   // esq baked as C-in
        }
#pragma unroll
        for (int dc = 0; dc < 8; ++dc) {
            // depth-1 B load from L2-resident image (compiler pipelines across unroll)
            const char* tb = ebase + ((size_t)(ct * 8 + dc) << 14) + loff;
            short8 b[4];
#pragma unroll
            for (int cf = 0; cf < 4; ++cf)
                b[cf] = *(const short8*)(tb + cf * 256);

            const int kb = dc * 64 + g * 16;
            short8 a[2];
#pragma unroll
            for (int rf = 0; rf < 2; ++rf) {
                int row = wr * 32 + rf * 16 + col;
                a[rf] = *(const short8*)(zhb + row * 512 + (kb ^ asw));
            }
#pragma unroll
            for (int rf = 0; rf < 2; ++rf)
#pragma unroll
                for (int cf = 0; cf < 4; ++cf)
                    acc[rf][cf] = __builtin_amdgcn_mfma_f32_16x16x32_bf16(
                        a[rf], b[cf], acc[rf][cf], 0, 0, 0);

            if (dc == 7) {
                // ---- per-ct append phase: wave-local threshold, no barrier ----
                const u32 cc0 = ((u32)ct << 8) + cbase;
#pragma unroll
                for (int rf = 0; rf < 2; ++rf)
#pragma unroll
                    for (int i = 0; i < 4; ++i) {
                        float m = fminf(fminf(acc[rf][0][i], acc[rf][1][i]),
                                        fminf(acc[rf][2][i], acc[rf][3][i]));
                        m = fminf(m, __shfl_xor(m, 1, 64));
                        m = fminf(m, __shfl_xor(m, 2, 64));
                        m = fminf(m, __shfl_xor(m, 4, 64));
                        m = fminf(m, __shfl_xor(m, 8, 64));
                        float wnew = fminf(wrun[rf][i], m);
                        wrun[rf][i] = wnew;
                        float tv = __fadd_rn(wnew, MARGIN);
                        int row = wr * 32 + rf * 16 + g * 4 + i;
#pragma unroll
                        for (int cf = 0; cf < 4; ++cf) {
                            if (acc[rf][cf][i] <= tv) {
                                u32 pos = atomicAdd(&cnt[row], 1u);
                                if (pos < (u32)CAP) {
                                    cand_s[row * CAP + pos] = acc[rf][cf][i];
                                    cand_i[row * CAP + pos] = cc0 + (u32)(cf * 16);
                                }
                            }
                        }
                    }
            }
        }
    }
    __syncthreads();   // all appends complete

    // ---- finalize: per row, min over appended set (contains each wave's min => global
    //      min present); threshold; survivors; winner or flag ----
    if (t < RB) {
        u32 c  = cnt[t];
        u32 cc = c < (u32)CAP ? c : (u32)CAP;
        float best = 3.0e38f;
        for (u32 i = 0; i < cc; ++i) best = fminf(best, cand_s[t * CAP + i]);
        float thr = __fadd_rn(best, MARGIN);
        u32 surv[8];
        int sc = 0;
        u32 win = 0u;
        float bs = 3.0e38f;
        for (u32 i = 0; i < cc; ++i) {
            float s = cand_s[t * CAP + i];
            u32  ki = cand_i[t * CAP + i];
            if (s <= thr) {
                if (sc < 8) surv[sc] = ki;
                ++sc;
            }
            if (s < bs) { bs = s; win = ki; }
        }
        u32 row_g = (u32)(r0 + t);
        if (c > (u32)CAP || sc > 8) {
            u32 pos = atomicAdd(flag_cnt, 1u);
            flag_list[pos] = row_g;                         // mode 0 = full scan
        } else if (sc >= 2) {
            u32 pos = atomicAdd(flag_cnt, 1u);
            flag_list[pos] = row_g | ((u32)sc << 20);
            for (int j = 0; j < sc; ++j) cand_g[(size_t)row_g * 8 + j] = surv[j];
        }
        kst[t] = win;
    }
    __syncthreads();

    // ---- gather winners (resolve overwrites flagged rows) ----
    const float4* E4 = (const float4*)E;
    float4* O4 = (float4*)out;
#pragma unroll
    for (int q = 0; q < 8; ++q) {
        int idx = t + 512 * q;
        int row = idx >> 6, f4 = idx & 63;
        u32 k = kst[row] & 1023u;
        O4[(size_t)(r0 + row) * 64 + f4] = E4[(size_t)k * 64 + f4];
    }
}

// ---------------- resolve: ET coalesced full scan + 8-lane candidate dots (r12) ----------
__device__ __forceinline__ u64 exact_key_serial(const float4* __restrict__ zr4,
                                                const float* __restrict__ E,
                                                const float* __restrict__ esq,
                                                float zs, u32 k) {
    const float4* er4 = (const float4*)(E + (size_t)k * D_);
    float c = 0.f;
#pragma unroll 8
    for (int q = 0; q < 64; ++q) {
        float4 a = zr4[q], b = er4[q];
        c = fmaf(a.x, b.x, c);
        c = fmaf(a.y, b.y, c);
        c = fmaf(a.z, b.z, c);
        c = fmaf(a.w, b.w, c);
    }
    float dist = __fadd_rn(__fsub_rn(zs, __fmul_rn(2.0f, c)), esq[k]);
    return ((u64)__float_as_uint(dist) << 32) | (u64)k;
}

__global__ __launch_bounds__(256)
void resolve_kernel(const float* __restrict__ Z, const float* __restrict__ E,
                    const float* __restrict__ esq, const u32* __restrict__ flag_cnt,
                    const u32* __restrict__ flag_list,
                    const u32* __restrict__ cand_g, const float* __restrict__ ET,
                    int use_et, float* __restrict__ out) {
    __shared__ float zbuf[4][256];
    const int lane = threadIdx.x & 63;
    const int wsl  = threadIdx.x >> 6;
    const int wid  = (blockIdx.x * 256 + threadIdx.x) >> 6;
    const int nw   = (gridDim.x * 256) >> 6;
    const u32 nf = flag_cnt[0];

    const int grp = lane >> 3, sub = lane & 7;
    const float4* E4 = (const float4*)E;
    float4* O4 = (float4*)out;

    for (u32 i = wid; i < nf; i += nw) {
        u32 e    = flag_list[i];
        u32 row  = e & 0xFFFFFu;
        u32 mode = e >> 20;
        const float* zr = Z + (size_t)row * D_;
        const float4* zr4 = (const float4*)zr;

        float r = 0.f;
        {
            int cidx = lane & 15, blk = cidx >> 3, j = cidx & 7;
            if (lane < 16) {
                const float* q = zr + blk * 128 + j;
                r = sqr_rn(q[0]);
                for (int ii = 8; ii < 128; ii += 8) r = __fadd_rn(r, sqr_rn(q[ii]));
            }
        }
        {
            float o = __shfl_xor(r, 1, 64);  r = __fadd_rn(r, o);
            o = __shfl_xor(r, 2, 64);        r = __fadd_rn(r, o);
            o = __shfl_xor(r, 4, 64);        r = __fadd_rn(r, o);
            o = __shfl_xor(r, 8, 64);        r = __fadd_rn(r, o);
        }
        float zs = __shfl(r, 0, 64);

        u64 best = ~0ull;
        if (mode == 0u) {
            if (use_et) {
                *(float4*)&zbuf[wsl][lane * 4] = zr4[lane];
                asm volatile("s_waitcnt lgkmcnt(0)" ::: "memory");
                const float4* ET4 = (const float4*)ET;
#pragma unroll
                for (int b = 0; b < 4; ++b) {
                    int k0 = b * 256 + lane * 4;
                    float c0 = 0.f, c1 = 0.f, c2 = 0.f, c3 = 0.f;
#pragma unroll 4
                    for (int d = 0; d < 256; ++d) {
                        float zd = zbuf[wsl][d];
                        float4 ev = ET4[d * 256 + b * 64 + lane];
                        c0 = fmaf(zd, ev.x, c0);
                        c1 = fmaf(zd, ev.y, c1);
                        c2 = fmaf(zd, ev.z, c2);
                        c3 = fmaf(zd, ev.w, c3);
                    }
                    float cc[4] = {c0, c1, c2, c3};
#pragma unroll
                    for (int j = 0; j < 4; ++j) {
                        u32 k = (u32)(k0 + j);
                        float dist = __fadd_rn(__fsub_rn(zs, __fmul_rn(2.0f, cc[j])), esq[k]);
                        u64 key = ((u64)__float_as_uint(dist) << 32) | (u64)k;
                        if (key < best) best = key;
                    }
                }
            } else {
                for (u32 k = (u32)lane; k < (u32)K_; k += 64u) {
                    u64 key = exact_key_serial(zr4, E, esq, zs, k);
                    if (key < best) best = key;
                }
            }
#pragma unroll
            for (int off = 32; off >= 1; off >>= 1) {
                u64 o = __shfl_xor(best, off, 64);
                if (o < best) best = o;
            }
        } else {
            if ((u32)grp < mode) {
                u32 k = cand_g[(size_t)row * 8 + grp];
                const float4* er4 = (const float4*)(E + (size_t)k * D_);
                float c = 0.f;
#pragma unroll
                for (int q = 0; q < 8; ++q) {
                    float4 a = zr4[sub * 8 + q], b = er4[sub * 8 + q];
                    c = fmaf(a.x, b.x, c);
                    c = fmaf(a.y, b.y, c);
                    c = fmaf(a.z, b.z, c);
                    c = fmaf(a.w, b.w, c);
                }
                c = __fadd_rn(c, __shfl_xor(c, 1, 64));
                c = __fadd_rn(c, __shfl_xor(c, 2, 64));
                c = __fadd_rn(c, __shfl_xor(c, 4, 64));
                float dist = __fadd_rn(__fsub_rn(zs, __fmul_rn(2.0f, c)), esq[k]);
                best = ((u64)__float_as_uint(dist) << 32) | (u64)k;
            }
            {
                u64 o = __shfl_xor(best, 8, 64);  if (o < best) best = o;
                o = __shfl_xor(best, 16, 64);     if (o < best) best = o;
                o = __shfl_xor(best, 32, 64);     if (o < best) best = o;
            }
        }
        u32 kw = (u32)(best & 0xffffffffu);
        O4[(size_t)row * 64 + lane] = E4[(size_t)kw * 64 + lane];
    }
}

extern "C" void kernel_launch(void* const* d_in, const int* in_sizes, int n_in,
                              void* d_out, int out_size, void* d_ws, size_t ws_size,
                              hipStream_t stream) {
    const float* Z = (const float*)d_in[0];
    const float* E = (const float*)d_in[1];
    float* out = (float*)d_out;

    float* esq       = (float*)d_ws;                              // 4 KB
    u16*   EhImg     = (u16*)((char*)d_ws + 4096);                // 512 KB
    u32*   flag_cnt  = (u32*)((char*)d_ws + 528384);              // 256 B
    u32*   flag_list = (u32*)((char*)d_ws + 528640);              // 512 KB
    u32*   cand_g    = (u32*)((char*)d_ws + 1052928);             // 4 MB
    float* ET        = (float*)((char*)d_ws + 5247232);           // 1 MB (if it fits)
    int use_et = (ws_size >= (size_t)(5247232 + 1048576)) ? 1 : 0;

    prep_all<<<(K_ * 8) / 256, 256, 0, stream>>>(E, EhImg, esq, flag_cnt);
    if (use_et)
        prep_et<<<(K_ * D_) / 256, 256, 0, stream>>>(E, ET);

    const int SMEM = 41472;
    hipFuncSetAttribute((const void*)vq_main,
                        hipFuncAttributeMaxDynamicSharedMemorySize, SMEM);
    vq_main<<<N_ / RB, 512, SMEM, stream>>>(Z, EhImg, esq, E,
                                            flag_cnt, flag_list, cand_g, out);

    resolve_kernel<<<1024, 256, 0, stream>>>(Z, E, esq, flag_cnt, flag_list,
                                             cand_g, ET, use_et, out);
}